// Round 7
// baseline (652.414 us; speedup 1.0000x reference)
//
#include <hip/hip_runtime.h>
#include <math.h>

#define NHID  1024
#define NCLS  224
#define NTPC  225
#define BATCH 2048

#define KSPLIT 8                     // K-chunks of 128 rows
#define KCH    128
#define NTILES (BATCH / 16)
#define NBOT_BLOCKS (NCLS * KSPLIT)      // 1792
#define NTOP_BLOCKS (NTILES * KSPLIT)    // 1024

#define YTS 224                      // top slab row stride (floats)
#define YBS 228                      // bottom slab row stride (padded)
#define YTOPK (BATCH * YTS)
#define YBOTK (BATCH * YBS)

#define RPAD 228                     // padded LDS W row: 912 B = 57 x 16B
#define WSLOT (16 * RPAD)            // 3648 floats per 16-row slot
#define XS_OFF (2 * WSLOT)
#define LDS_FLOATS (2 * WSLOT + 2 * 2048)   // 45568 B -> 3 blocks/CU

// ws layout (bytes):
#define CLS_OFF  0
#define POS_OFF  8192
#define LIST_OFF 16384
#define OFFS_OFF 24576
#define YTOP_OFF 32768
#define YTOP_BYTES (KSPLIT * YTOPK * 4)
#define YBOT_OFF (YTOP_OFF + YTOP_BYTES)
#define YBOT_BYTES (KSPLIT * YBOTK * 4)

#define SBAR() __builtin_amdgcn_s_barrier()
#define LGKM0() do { asm volatile("s_waitcnt lgkmcnt(0)" ::: "memory"); \
                     __builtin_amdgcn_sched_barrier(0); } while (0)
#define VM15() do { asm volatile("s_waitcnt vmcnt(15)" ::: "memory"); \
                    __builtin_amdgcn_sched_barrier(0); } while (0)
#define VM0()  do { asm volatile("s_waitcnt vmcnt(0)" ::: "memory"); \
                    __builtin_amdgcn_sched_barrier(0); } while (0)

__device__ __forceinline__ void dma16(const float* src, float* dst) {
    __builtin_amdgcn_global_load_lds(
        (const __attribute__((address_space(1))) void*)src,
        (__attribute__((address_space(3))) void*)dst, 16, 0, 0);
}

// DMA one 16-row W group (RBF floats/row in global) into a padded-row LDS
// slot (RPAD floats/row). LDS dest is linear (base + lane*16, m104); the
// row padding is achieved on the SOURCE side (per-lane addresses, m173):
// 16B-block c = 64*i + lane maps to row c/57, block c%57. 912 blocks =
// 14 full wave-issues + one 16-lane issue. Sources that would run past the
// W array end (only the final chunk's last block) are clamped in-bounds;
// the one real value displaced by the clamp is patched by run_tiles.
template<int RBF>
__device__ __forceinline__ void issue_group(const float* chunk, const float* wend,
                                            float* wslot, int g, int l) {
    const float* gb = chunk + (size_t)g * 16 * RBF;
#pragma unroll
    for (int i = 0; i < 15; ++i) {
        if (i < 14 || l < 16) {
            const int c = 64 * i + l;
            const int row = c / 57;
            const int b = c - row * 57;
            const float* src = gb + row * RBF + b * 4;
            if (src + 4 > wend) src = wend - 4;
            dma16(src, wslot + i * 256);
        }
    }
}

// ---------------------------------------------------------------------------
// Pass 0: label decode (int32/int64 autodetect), class/pos, group-by-class.
// ---------------------------------------------------------------------------
__global__ __launch_bounds__(256) void group_kernel(const int* __restrict__ labels,
                                                    int* __restrict__ cls,
                                                    int* __restrict__ pos,
                                                    int* __restrict__ list,
                                                    int* __restrict__ offs) {
    __shared__ int cnt[NCLS];
    __shared__ int sc[256];
    __shared__ int bex[NCLS];
    __shared__ int nz;
    const int tid = threadIdx.x;
    if (tid == 0) nz = 0;
    for (int j = tid; j < NCLS; j += 256) cnt[j] = 0;
    __syncthreads();
    int loc = 0;
    for (int k = 0; k < 4; ++k) {
        int i = tid + 256 * k;
        if (labels[2 * i + 1] != 0) loc = 1;
    }
    if (loc) atomicOr(&nz, 1);
    __syncthreads();
    const bool is64 = (nz == 0);
    int myc[8], myr[8];
#pragma unroll
    for (int k = 0; k < 8; ++k) {
        int i = tid + 256 * k;
        int l = is64 ? labels[2 * i] : labels[i];
        int c = l / NTPC;
        cls[i] = c;
        pos[i] = l - c * NTPC;
        myc[k] = c;
        myr[k] = atomicAdd(&cnt[c], 1);
    }
    __syncthreads();
    int v = (tid < NCLS) ? cnt[tid] : 0;
    sc[tid] = v;
    __syncthreads();
    for (int off = 1; off < 256; off <<= 1) {
        int u = (tid >= off) ? sc[tid - off] : 0;
        __syncthreads();
        sc[tid] += u;
        __syncthreads();
    }
    if (tid < NCLS) {
        int ex = sc[tid] - v;
        bex[tid] = ex;
        offs[tid] = ex;
    }
    if (tid == 0) offs[NCLS] = BATCH;
    __syncthreads();
#pragma unroll
    for (int k = 0; k < 8; ++k) {
        int i = tid + 256 * k;
        list[bex[myc[k]] + myr[k]] = i;
    }
}

// ---------------------------------------------------------------------------
// Pass 1: K-split partial GEMMs, chunk = 128 rows, KSPLIT = 8, 2816 blocks.
// Rounds 0-6 invariant: every consumer-side inner-loop variant lands at
// 113-135us, VALUBusy 17-21% -- compute waves are latency-bound on their
// OWN in-flight cold W loads (in-order vmcnt, <=16 deep). Fix: single
// producer wave (w==3) DMAs W into LDS via global_load_lds, 16-row groups,
// double-buffered, counted vmcnt(15) (never drained mid-loop; raw s_barrier
// so the compiler's __syncthreads vmcnt(0) drain is avoided). Consumers
// compute purely from LDS: per row per wave 1 aligned W ds_read_b128
// (912B-padded rows, conflict-free) + 1 broadcast x ds_read_b128 + 16 FMA.
// Wave w owns samples 4w..4w+3; lane l owns cols 4l..4l+3 (clamped).
// Outputs: float4 stores into per-k slabs; finalize sums slabs.
// Block-index transpose (c = bi % 224): chunks of one target on one XCD.
// ---------------------------------------------------------------------------
template<int YC, int YS, int RBF, bool BOT>
__device__ __forceinline__ void run_tiles(const float* __restrict__ x,
                                          const float* __restrict__ chunk,
                                          const float* __restrict__ wend,
                                          float* __restrict__ yk,
                                          const int* __restrict__ list,
                                          int o, int n, int hbase,
                                          float* __restrict__ lds) {
    float* wlds = lds;
    float* xsb  = lds + XS_OFF;
    const int tid = threadIdx.x;
    const int w = tid >> 6, l = tid & 63;
    const bool pw = (w == 3);                   // producer wave
    const int r  = tid & 127;                   // staging row within chunk
    const int hs = tid >> 7;                    // sample-half
    const int rq = (r >> 1) & 3;                // x staging swizzle key
    const int lq = min(4 * l, RPAD - 4);        // lane col-quad (clamped)
    const bool fixtail = BOT && (chunk + 128 * RBF == wend);

    for (int sb = 0; sb < n; sb += 32) {
        const int nb = min(n - sb, 32);
        const int ntile = (nb + 15) >> 4;

        // ---- stage x tiles (all waves), swizzled for broadcast reads ----
#pragma unroll
        for (int t = 0; t < 2; ++t) if (t < ntile) {
            int sid[8];
#pragma unroll
            for (int j = 0; j < 8; ++j) {
                const int idx = sb + t * 16 + hs * 8 + j;
                sid[j] = BOT ? list[o + min(idx, n - 1)] : (o + min(idx, n - 1));
            }
            const float* xr = x + hbase + r;
            float* xst = xsb + t * 2048;
#pragma unroll
            for (int j = 0; j < 8; ++j) {
                const int i = hs * 8 + j;
                xst[(r << 4) + ((((i >> 2) ^ rq) << 2) | (i & 3))] =
                    xr[(size_t)sid[j] * NHID];
            }
        }
        LGKM0();
        if (pw) {                               // prologue: 2 groups in flight
            issue_group<RBF>(chunk, wend, wlds, 0, l);
            issue_group<RBF>(chunk, wend, wlds + WSLOT, 1, l);
        }

        float4 acc[2][4];
#pragma unroll
        for (int t = 0; t < 2; ++t)
#pragma unroll
            for (int s = 0; s < 4; ++s) acc[t][s] = make_float4(0.f, 0.f, 0.f, 0.f);

        for (int g = 0; g < 8; ++g) {
            if (pw) {
                if (g == 7) { VM0(); } else { VM15(); }   // group g landed
                if (fixtail && g == 7) {        // clamp displaced one value:
                    if (l == 0)                 // final row col 224 of botW
                        wlds[WSLOT + 15 * RPAD + 224] = wend[-1];
                    LGKM0();
                }
            }
            SBAR();                             // publish slot g&1
            const float* wl = wlds + (g & 1) * WSLOT;
#pragma unroll
            for (int t = 0; t < 2; ++t) if (t < ntile) {
                const float4* xq = (const float4*)(xsb + t * 2048);
#pragma unroll
                for (int j = 0; j < 16; ++j) {
                    const float4 wv = *(const float4*)(wl + j * RPAD + lq);
                    const float4 xv = xq[(g * 16 + j) * 4 + (w ^ ((j >> 1) & 3))];
                    acc[t][0].x = fmaf(xv.x, wv.x, acc[t][0].x);
                    acc[t][0].y = fmaf(xv.x, wv.y, acc[t][0].y);
                    acc[t][0].z = fmaf(xv.x, wv.z, acc[t][0].z);
                    acc[t][0].w = fmaf(xv.x, wv.w, acc[t][0].w);
                    acc[t][1].x = fmaf(xv.y, wv.x, acc[t][1].x);
                    acc[t][1].y = fmaf(xv.y, wv.y, acc[t][1].y);
                    acc[t][1].z = fmaf(xv.y, wv.z, acc[t][1].z);
                    acc[t][1].w = fmaf(xv.y, wv.w, acc[t][1].w);
                    acc[t][2].x = fmaf(xv.z, wv.x, acc[t][2].x);
                    acc[t][2].y = fmaf(xv.z, wv.y, acc[t][2].y);
                    acc[t][2].z = fmaf(xv.z, wv.z, acc[t][2].z);
                    acc[t][2].w = fmaf(xv.z, wv.w, acc[t][2].w);
                    acc[t][3].x = fmaf(xv.w, wv.x, acc[t][3].x);
                    acc[t][3].y = fmaf(xv.w, wv.y, acc[t][3].y);
                    acc[t][3].z = fmaf(xv.w, wv.z, acc[t][3].z);
                    acc[t][3].w = fmaf(xv.w, wv.w, acc[t][3].w);
                }
            }
            LGKM0();                            // all slot reads returned
            SBAR();                             // slot g&1 free
            if (pw && g + 2 < 8)
                issue_group<RBF>(chunk, wend, wlds + (g & 1) * WSLOT, g + 2, l);
        }

        // ---- store: float4 quads (slab rows 16B-strided; bottom lane 56's
        // cols 224-227 land in the YBS=228 pad, finalize reads < 225) ----
        const int cb = 4 * l;
#pragma unroll
        for (int t = 0; t < 2; ++t) if (t < ntile) {
#pragma unroll
            for (int jj = 0; jj < 4; ++jj) {
                const int it = 4 * w + jj;
                if (t * 16 + it < nb && cb < YC) {
                    const int gi = o + sb + t * 16 + it;
                    const int s = BOT ? list[gi] : gi;
                    *(float4*)(yk + (size_t)s * YS + cb) = acc[t][jj];
                }
            }
        }
    }
}

__global__ __launch_bounds__(256, 3) void partial_kernel(const float* __restrict__ x,
                                                         const float* __restrict__ Wt,
                                                         const float* __restrict__ Wb,
                                                         const int* __restrict__ list,
                                                         const int* __restrict__ offs,
                                                         float* __restrict__ ytop,
                                                         float* __restrict__ ybot) {
    __shared__ __align__(16) float lds[LDS_FLOATS];
    const int bi = blockIdx.x;
    if (bi < NBOT_BLOCKS) {
        const int c = bi % NCLS;        // 224 % 8 == 0 -> chunks of class c
        const int k = bi / NCLS;        // on one XCD
        const int o = offs[c];
        const int n = offs[c + 1] - o;
        if (n == 0) return;
        const float* chunk = Wb + (size_t)c * (NHID * NTPC) + (size_t)(k * KCH) * NTPC;
        const float* wend  = Wb + (size_t)NCLS * NHID * NTPC;
        run_tiles<NTPC, YBS, NTPC, true>(x, chunk, wend, ybot + (size_t)k * YBOTK,
                                         list, o, n, k * KCH, lds);
    } else {
        const int b2 = bi - NBOT_BLOCKS;
        const int st = b2 % NTILES;
        const int k  = b2 / NTILES;
        const float* chunk = Wt + (size_t)(k * KCH) * NCLS;
        const float* wend  = Wt + (size_t)NHID * NCLS;
        run_tiles<NCLS, YTS, NCLS, false>(x, chunk, wend, ytop + (size_t)k * YTOPK,
                                          list, st * 16, 16, k * KCH, lds);
    }
}

// ---------------------------------------------------------------------------
// Pass 2: per-sample k-slab reduction + dual softmax + product. One wave per
// sample. Bottom slabs have padded row stride YBS.
// ---------------------------------------------------------------------------
__global__ __launch_bounds__(256) void finalize_kernel(const float* __restrict__ ytop,
                                                       const float* __restrict__ ybot,
                                                       const float* __restrict__ bt,
                                                       const float* __restrict__ bb,
                                                       const int* __restrict__ cls,
                                                       const int* __restrict__ pos,
                                                       float* __restrict__ out) {
    const int w = threadIdx.x >> 6, l = threadIdx.x & 63;
    const int s = blockIdx.x * 4 + w;
    const int c = cls[s], p = pos[s];

    float v[4];
#pragma unroll
    for (int g = 0; g < 4; ++g) {
        int col = l + 64 * g;
        if (col < NCLS) {
            float a = bt[col];
#pragma unroll
            for (int k = 0; k < KSPLIT; ++k)
                a += ytop[(size_t)k * YTOPK + (size_t)s * YTS + col];
            v[g] = a;
        } else {
            v[g] = -INFINITY;
        }
    }
    float mx = fmaxf(fmaxf(v[0], v[1]), fmaxf(v[2], v[3]));
#pragma unroll
    for (int off = 32; off; off >>= 1) mx = fmaxf(mx, __shfl_xor(mx, off));
    float sum = 0.f, tc = 0.f;
#pragma unroll
    for (int g = 0; g < 4; ++g) {
        int col = l + 64 * g;
        float e = (col < NCLS) ? __expf(v[g] - mx) : 0.f;
        sum += e;
        if (col == c) tc = e;
    }
#pragma unroll
    for (int off = 32; off; off >>= 1) {
        sum += __shfl_xor(sum, off);
        tc  += __shfl_xor(tc, off);
    }
    const float tp = tc / sum;

#pragma unroll
    for (int g = 0; g < 4; ++g) {
        int col = l + 64 * g;
        if (col < NTPC) {
            float a = bb[c * NTPC + col];
#pragma unroll
            for (int k = 0; k < KSPLIT; ++k)
                a += ybot[(size_t)k * YBOTK + (size_t)s * YBS + col];
            v[g] = a;
        } else {
            v[g] = -INFINITY;
        }
    }
    mx = fmaxf(fmaxf(v[0], v[1]), fmaxf(v[2], v[3]));
#pragma unroll
    for (int off = 32; off; off >>= 1) mx = fmaxf(mx, __shfl_xor(mx, off));
    float bsum = 0.f, ep = 0.f;
#pragma unroll
    for (int g = 0; g < 4; ++g) {
        int col = l + 64 * g;
        float e = (col < NTPC) ? __expf(v[g] - mx) : 0.f;
        bsum += e;
        if (col == p) ep = e;
    }
#pragma unroll
    for (int off = 32; off; off >>= 1) bsum += __shfl_xor(bsum, off);
#pragma unroll
    for (int g = 0; g < 4; ++g)
        if (l + 64 * g == p) out[s] = tp * ep / bsum;
}

extern "C" void kernel_launch(void* const* d_in, const int* in_sizes, int n_in,
                              void* d_out, int out_size, void* d_ws, size_t ws_size,
                              hipStream_t stream) {
    const float* inputs = (const float*)d_in[0];
    const int*   labels = (const int*)d_in[1];
    const float* topW   = (const float*)d_in[2];
    const float* topB   = (const float*)d_in[3];
    const float* botW   = (const float*)d_in[4];
    const float* botB   = (const float*)d_in[5];
    float* out = (float*)d_out;

    char* ws   = (char*)d_ws;
    int*   cls = (int*)(ws + CLS_OFF);
    int*   pos = (int*)(ws + POS_OFF);
    int*   lst = (int*)(ws + LIST_OFF);
    int*   off = (int*)(ws + OFFS_OFF);
    float* ytop = (float*)(ws + YTOP_OFF);
    float* ybot = (float*)(ws + YBOT_OFF);

    // no memset: every slab entry read by finalize is overwritten by pass 1
    group_kernel<<<1, 256, 0, stream>>>(labels, cls, pos, lst, off);
    partial_kernel<<<NBOT_BLOCKS + NTOP_BLOCKS, 256, 0, stream>>>(
        inputs, topW, botW, lst, off, ytop, ybot);
    finalize_kernel<<<BATCH / 4, 256, 0, stream>>>(ytop, ybot, topB, botB, cls, pos, out);
}

// Round 9
// 478.325 us; speedup vs baseline: 1.3640x; 1.3640x over previous
//
#include <hip/hip_runtime.h>
#include <math.h>

#define NHID  1024
#define NCLS  224
#define NTPC  225
#define BATCH 2048

#define NTOP_BLOCKS 128              // sample-tiles of 16
#define NBOT_BLOCKS 224              // one block per class
#define NBLOCKS (NTOP_BLOCKS + NBOT_BLOCKS)

#define YTS 224                      // ytop row stride (floats)
#define YBS 228                      // ybot row stride (padded)

#define XPAD 20                      // xs row pad: 80B rows -> b128-aligned,
                                     // 8-way stage conflict (cheap, 16 instrs)
#define SACCP 228

// ws layout (bytes):
#define CLS_OFF  0
#define POS_OFF  8192
#define LIST_OFF 16384
#define OFFS_OFF 24576
#define YTOP_OFF 32768
#define YTOP_BYTES (BATCH * YTS * 4)
#define YBOT_OFF (YTOP_OFF + YTOP_BYTES)
#define YBOT_BYTES (BATCH * YBS * 4)

// ---------------------------------------------------------------------------
// Pass 0: label decode (int32/int64 autodetect), class/pos, group-by-class.
// ---------------------------------------------------------------------------
__global__ __launch_bounds__(256) void group_kernel(const int* __restrict__ labels,
                                                    int* __restrict__ cls,
                                                    int* __restrict__ pos,
                                                    int* __restrict__ list,
                                                    int* __restrict__ offs) {
    __shared__ int cnt[NCLS];
    __shared__ int sc[256];
    __shared__ int bex[NCLS];
    __shared__ int nz;
    const int tid = threadIdx.x;
    if (tid == 0) nz = 0;
    for (int j = tid; j < NCLS; j += 256) cnt[j] = 0;
    __syncthreads();
    int loc = 0;
    for (int k = 0; k < 4; ++k) {
        int i = tid + 256 * k;
        if (labels[2 * i + 1] != 0) loc = 1;
    }
    if (loc) atomicOr(&nz, 1);
    __syncthreads();
    const bool is64 = (nz == 0);
    int myc[8], myr[8];
#pragma unroll
    for (int k = 0; k < 8; ++k) {
        int i = tid + 256 * k;
        int l = is64 ? labels[2 * i] : labels[i];
        int c = l / NTPC;
        cls[i] = c;
        pos[i] = l - c * NTPC;
        myc[k] = c;
        myr[k] = atomicAdd(&cnt[c], 1);
    }
    __syncthreads();
    int v = (tid < NCLS) ? cnt[tid] : 0;
    sc[tid] = v;
    __syncthreads();
    for (int off = 1; off < 256; off <<= 1) {
        int u = (tid >= off) ? sc[tid - off] : 0;
        __syncthreads();
        sc[tid] += u;
        __syncthreads();
    }
    if (tid < NCLS) {
        int ex = sc[tid] - v;
        bex[tid] = ex;
        offs[tid] = ex;
    }
    if (tid == 0) offs[NCLS] = BATCH;
    __syncthreads();
#pragma unroll
    for (int k = 0; k < 8; ++k) {
        int i = tid + 256 * k;
        list[bex[myc[k]] + myr[k]] = i;
    }
}

// ---------------------------------------------------------------------------
// Pass 1: stream GEMM, one block per class (bottom) / per 16-sample tile
// (top). Rounds 0-7 lesson: K-split 16-sample tiles with gather barriers
// never exceeded ~1.4 TB/s effective fetch; the W read must look like m13's
// streaming pattern. Here each bottom block streams its class's FULL 900KB
// W once, contiguously, with NO barrier in the K loop; y is written once
// (no slabs / atomics / k-sum readback: -75MB HBM).
// 512 thr = 8 waves = 4 row-groups x 2 sample-groups. Lane l owns cols
// {l, l+64, l+128, 192+l}: every W access = 256B contiguous 4B-aligned
// wave-load (no 16B-alignment hazard: r4/r7 lesson). 2-deep ping-pong of
// 4-row groups (wA/wB, compile-time indices). Row-group partials reduced
// by LDS atomicAdd at the end.
// x: staged transposed xs[row][sample] (pad 20 -> aligned b128 broadcast
// reads, 2/row/wave), in 512-row halves (LDS 55KB -> 2 blocks/CU).
// Top blocks (grid-first): 16/XCD share the 0.92MB Wt via L2.
// ---------------------------------------------------------------------------
template<int YC, int YS, bool BOT>
__device__ __forceinline__ void run_class(const float* __restrict__ x,
                                          const float* __restrict__ W,
                                          float* __restrict__ y,
                                          const int* __restrict__ list,
                                          int o, int n,
                                          float* __restrict__ xs,
                                          float* __restrict__ sacc) {
    const int tid = threadIdx.x;                // 0..511
    const int wv  = tid >> 6;                   // wave 0..7
    const int l   = tid & 63;
    const int r   = wv & 3;                     // row-group (rows == r mod 4)
    const int g   = wv >> 2;                    // sample-group: samples 8g..8g+7
    const int c3  = min(192 + l, YC - 1);       // clamped 4th col
    const bool c3ok = (192 + l < YC);

    for (int base = 0; base < n; base += 16) {
        const int nt = min(n - base, 16);
        __syncthreads();                        // prior store done with sacc
        for (int i = tid; i < 16 * SACCP; i += 512) sacc[i] = 0.f;

        float acc[8][4];
#pragma unroll
        for (int si = 0; si < 8; ++si)
#pragma unroll
            for (int c = 0; c < 4; ++c) acc[si][c] = 0.f;

#pragma unroll 1
        for (int half = 0; half < 2; ++half) {
            const int hb = half * 512;
            if (half) __syncthreads();          // compute(half0) done with xs
            // ---- stage: xs[lh][s], 1 float/thread/sample, coalesced ----
#pragma unroll
            for (int s = 0; s < 16; ++s) {
                const int si = BOT ? list[o + min(base + s, n - 1)]
                                   : (o + min(base + s, n - 1));
                xs[tid * XPAD + s] = x[(size_t)si * NHID + hb + tid];
            }
            __syncthreads();

            // ---- stream W rows (this wave: local rows 4t+r, t=0..127),
            //      2-deep ping-pong of 4-row groups ----
            const float* Wh = W + (size_t)hb * YC;
            float wA[16], wB[16];
            auto LOADG = [&](float (&dst)[16], int gi) {
                const int gc = min(gi, 31);     // dead-final clamp
#pragma unroll
                for (int jt = 0; jt < 4; ++jt) {
                    const float* row = Wh + (size_t)(16 * gc + 4 * jt + r) * YC;
                    dst[4 * jt + 0] = row[l];
                    dst[4 * jt + 1] = row[l + 64];
                    dst[4 * jt + 2] = row[l + 128];
                    dst[4 * jt + 3] = row[c3];
                }
            };
            auto COMPG = [&](const float (&wvk)[16], int gi) {
#pragma unroll
                for (int jt = 0; jt < 4; ++jt) {
                    const int lh = 16 * gi + 4 * jt + r;
                    const float4 xa = *(const float4*)(xs + lh * XPAD + 8 * g);
                    const float4 xb = *(const float4*)(xs + lh * XPAD + 8 * g + 4);
                    const float w0 = wvk[4 * jt + 0], w1 = wvk[4 * jt + 1];
                    const float w2 = wvk[4 * jt + 2], w3 = wvk[4 * jt + 3];
                    acc[0][0] = fmaf(xa.x, w0, acc[0][0]);
                    acc[0][1] = fmaf(xa.x, w1, acc[0][1]);
                    acc[0][2] = fmaf(xa.x, w2, acc[0][2]);
                    acc[0][3] = fmaf(xa.x, w3, acc[0][3]);
                    acc[1][0] = fmaf(xa.y, w0, acc[1][0]);
                    acc[1][1] = fmaf(xa.y, w1, acc[1][1]);
                    acc[1][2] = fmaf(xa.y, w2, acc[1][2]);
                    acc[1][3] = fmaf(xa.y, w3, acc[1][3]);
                    acc[2][0] = fmaf(xa.z, w0, acc[2][0]);
                    acc[2][1] = fmaf(xa.z, w1, acc[2][1]);
                    acc[2][2] = fmaf(xa.z, w2, acc[2][2]);
                    acc[2][3] = fmaf(xa.z, w3, acc[2][3]);
                    acc[3][0] = fmaf(xa.w, w0, acc[3][0]);
                    acc[3][1] = fmaf(xa.w, w1, acc[3][1]);
                    acc[3][2] = fmaf(xa.w, w2, acc[3][2]);
                    acc[3][3] = fmaf(xa.w, w3, acc[3][3]);
                    acc[4][0] = fmaf(xb.x, w0, acc[4][0]);
                    acc[4][1] = fmaf(xb.x, w1, acc[4][1]);
                    acc[4][2] = fmaf(xb.x, w2, acc[4][2]);
                    acc[4][3] = fmaf(xb.x, w3, acc[4][3]);
                    acc[5][0] = fmaf(xb.y, w0, acc[5][0]);
                    acc[5][1] = fmaf(xb.y, w1, acc[5][1]);
                    acc[5][2] = fmaf(xb.y, w2, acc[5][2]);
                    acc[5][3] = fmaf(xb.y, w3, acc[5][3]);
                    acc[6][0] = fmaf(xb.z, w0, acc[6][0]);
                    acc[6][1] = fmaf(xb.z, w1, acc[6][1]);
                    acc[6][2] = fmaf(xb.z, w2, acc[6][2]);
                    acc[6][3] = fmaf(xb.z, w3, acc[6][3]);
                    acc[7][0] = fmaf(xb.w, w0, acc[7][0]);
                    acc[7][1] = fmaf(xb.w, w1, acc[7][1]);
                    acc[7][2] = fmaf(xb.w, w2, acc[7][2]);
                    acc[7][3] = fmaf(xb.w, w3, acc[7][3]);
                }
            };

            LOADG(wA, 0);
#pragma unroll 1
            for (int gi = 0; gi < 32; gi += 2) {
                LOADG(wB, gi + 1);
                COMPG(wA, gi);
                LOADG(wA, gi + 2);
                COMPG(wB, gi + 1);
            }
        }

        // ---- reduce 4 row-group waves into sacc (LDS f32 atomics) ----
#pragma unroll
        for (int si = 0; si < 8; ++si) {
            float* sr = sacc + (8 * g + si) * SACCP;
            atomicAdd(sr + l,        acc[si][0]);
            atomicAdd(sr + l + 64,   acc[si][1]);
            atomicAdd(sr + l + 128,  acc[si][2]);
            if (c3ok) atomicAdd(sr + 192 + l, acc[si][3]);
        }
        __syncthreads();

        // ---- store: sacc -> y (once; no K-slabs) ----
#pragma unroll 1
        for (int i = tid; i < nt * 256; i += 512) {
            const int s = i >> 8, col = i & 255;
            if (col < YC) {
                const int si = BOT ? list[o + base + s] : (o + base + s);
                y[(size_t)si * YS + col] = sacc[s * SACCP + col];
            }
        }
    }
}

__global__ __launch_bounds__(512, 4) void partial_kernel(const float* __restrict__ x,
                                                         const float* __restrict__ Wt,
                                                         const float* __restrict__ Wb,
                                                         const int* __restrict__ list,
                                                         const int* __restrict__ offs,
                                                         float* __restrict__ ytop,
                                                         float* __restrict__ ybot) {
    __shared__ __align__(16) float xs[512 * XPAD];      // 40 KB
    __shared__ __align__(16) float sacc[16 * SACCP];    // 14.25 KB
    const int bi = blockIdx.x;
    if (bi < NTOP_BLOCKS) {
        // top tiles first: 16 blocks/XCD share Wt (0.92MB) through L2
        run_class<NCLS, YTS, false>(x, Wt, ytop, list, bi * 16, 16, xs, sacc);
    } else {
        const int c = bi - NTOP_BLOCKS;
        const int o = offs[c];
        const int n = offs[c + 1] - o;
        run_class<NTPC, YBS, true>(x, Wb + (size_t)c * (NHID * NTPC), ybot,
                                   list, o, n, xs, sacc);
    }
}

// ---------------------------------------------------------------------------
// Pass 2: per-sample dual softmax + product. One wave per sample.
// ---------------------------------------------------------------------------
__global__ __launch_bounds__(256) void finalize_kernel(const float* __restrict__ ytop,
                                                       const float* __restrict__ ybot,
                                                       const float* __restrict__ bt,
                                                       const float* __restrict__ bb,
                                                       const int* __restrict__ cls,
                                                       const int* __restrict__ pos,
                                                       float* __restrict__ out) {
    const int w = threadIdx.x >> 6, l = threadIdx.x & 63;
    const int s = blockIdx.x * 4 + w;
    const int c = cls[s], p = pos[s];

    float v[4];
#pragma unroll
    for (int g = 0; g < 4; ++g) {
        int col = l + 64 * g;
        v[g] = (col < NCLS) ? ytop[(size_t)s * YTS + col] + bt[col] : -INFINITY;
    }
    float mx = fmaxf(fmaxf(v[0], v[1]), fmaxf(v[2], v[3]));
#pragma unroll
    for (int off = 32; off; off >>= 1) mx = fmaxf(mx, __shfl_xor(mx, off));
    float sum = 0.f, tc = 0.f;
#pragma unroll
    for (int g = 0; g < 4; ++g) {
        int col = l + 64 * g;
        float e = (col < NCLS) ? __expf(v[g] - mx) : 0.f;
        sum += e;
        if (col == c) tc = e;
    }
#pragma unroll
    for (int off = 32; off; off >>= 1) {
        sum += __shfl_xor(sum, off);
        tc  += __shfl_xor(tc, off);
    }
    const float tp = tc / sum;

#pragma unroll
    for (int g = 0; g < 4; ++g) {
        int col = l + 64 * g;
        v[g] = (col < NTPC) ? ybot[(size_t)s * YBS + col] + bb[c * NTPC + col]
                            : -INFINITY;
    }
    mx = fmaxf(fmaxf(v[0], v[1]), fmaxf(v[2], v[3]));
#pragma unroll
    for (int off = 32; off; off >>= 1) mx = fmaxf(mx, __shfl_xor(mx, off));
    float bsum = 0.f, ep = 0.f;
#pragma unroll
    for (int g = 0; g < 4; ++g) {
        int col = l + 64 * g;
        float e = (col < NTPC) ? __expf(v[g] - mx) : 0.f;
        bsum += e;
        if (col == p) ep = e;
    }
#pragma unroll
    for (int off = 32; off; off >>= 1) bsum += __shfl_xor(bsum, off);
#pragma unroll
    for (int g = 0; g < 4; ++g)
        if (l + 64 * g == p) out[s] = tp * ep / bsum;
}

extern "C" void kernel_launch(void* const* d_in, const int* in_sizes, int n_in,
                              void* d_out, int out_size, void* d_ws, size_t ws_size,
                              hipStream_t stream) {
    const float* inputs = (const float*)d_in[0];
    const int*   labels = (const int*)d_in[1];
    const float* topW   = (const float*)d_in[2];
    const float* topB   = (const float*)d_in[3];
    const float* botW   = (const float*)d_in[4];
    const float* botB   = (const float*)d_in[5];
    float* out = (float*)d_out;

    char* ws   = (char*)d_ws;
    int*   cls = (int*)(ws + CLS_OFF);
    int*   pos = (int*)(ws + POS_OFF);
    int*   lst = (int*)(ws + LIST_OFF);
    int*   off = (int*)(ws + OFFS_OFF);
    float* ytop = (float*)(ws + YTOP_OFF);
    float* ybot = (float*)(ws + YBOT_OFF);

    // no memset: every y row read by finalize is fully written by pass 1
    group_kernel<<<1, 256, 0, stream>>>(labels, cls, pos, lst, off);
    partial_kernel<<<NBLOCKS, 512, 0, stream>>>(
        inputs, topW, botW, lst, off, ytop, ybot);
    finalize_kernel<<<BATCH / 4, 256, 0, stream>>>(ytop, ybot, topB, botB, cls, pos, out);
}